// Round 2
// baseline (571.004 us; speedup 1.0000x reference)
//
#include <hip/hip_runtime.h>

#define NROWS 13107200          // 32*640*640
#define HW    409600            // 640*640
#define N4    (NROWS/4)
#define CBINS 8192              // top-13-bit histogram
#define FBINS 4096              // next-12-bit fine histogram
#define BLOCKS 1280             // 5 blocks/CU resident (32KB LDS); N4/(1280*256)=10 iters exactly
#define TPB    256

struct Ctl {
  double posLoss;     // sum over pos rows of se*w
  double sumW;        // sum over pos rows of w
  double sumAbove;    // exact sum of se in coarse bins > cutoff
  unsigned posCount;
  unsigned negCount;
  unsigned cutoffBin;
  unsigned kRemain;
  unsigned kSel;
  unsigned pad0, pad1, pad2;
};

__device__ inline float wredf(float v) {
  #pragma unroll
  for (int o = 32; o > 0; o >>= 1) v += __shfl_down(v, o, 64);
  return v;
}
__device__ inline unsigned wredu(unsigned v) {
  #pragma unroll
  for (int o = 32; o > 0; o >>= 1) v += (unsigned)__shfl_down((int)v, o, 64);
  return v;
}

// Pass 1: pos stats + coarse histogram (top 13 bits of float bits of se) over negatives.
__global__ __launch_bounds__(TPB)
void pass1(const float* __restrict__ pred, const float* __restrict__ vmk,
           const float* __restrict__ wgt, Ctl* __restrict__ ctl,
           unsigned* __restrict__ hist)
{
  __shared__ unsigned lh[CBINS];
  for (int j = threadIdx.x; j < CBINS; j += TPB) lh[j] = 0;
  __syncthreads();

  float posLoss = 0.f, sumW = 0.f;
  unsigned posC = 0, negC = 0;
  const int stride = gridDim.x * TPB;
  for (int g = blockIdx.x * TPB + threadIdx.x; g < N4; g += stride) {
    const int i = g << 2;
    const int b = i / HW;          // group of 4 rows never crosses a batch (HW % 4 == 0)
    const int hw = i - b * HW;
    const size_t base = (size_t)b * (size_t)(2 * HW) + (size_t)hw;
    const float4 w4 = *(const float4*)(wgt + i);
    const float4 p0 = *(const float4*)(pred + base);
    const float4 p1 = *(const float4*)(pred + base + HW);
    const float4 t0 = *(const float4*)(vmk + base);
    const float4 t1 = *(const float4*)(vmk + base + HW);
    float se[4], wv[4];
    {
      float a, c;
      a = p0.x - t0.x; c = p1.x - t1.x; se[0] = a*a + c*c;
      a = p0.y - t0.y; c = p1.y - t1.y; se[1] = a*a + c*c;
      a = p0.z - t0.z; c = p1.z - t1.z; se[2] = a*a + c*c;
      a = p0.w - t0.w; c = p1.w - t1.w; se[3] = a*a + c*c;
    }
    wv[0] = w4.x; wv[1] = w4.y; wv[2] = w4.z; wv[3] = w4.w;
    #pragma unroll
    for (int c = 0; c < 4; ++c) {
      const float w = wv[c];
      const float s = se[c];
      if (w > 0.f)       { posC++; sumW += w; posLoss += s * w; }
      else if (w == 0.f) { negC++; atomicAdd(&lh[__float_as_uint(s) >> 19], 1u); }
      // w < 0: neither pos nor neg (mirrors reference semantics)
    }
  }

  posLoss = wredf(posLoss); sumW = wredf(sumW);
  posC = wredu(posC); negC = wredu(negC);
  if ((threadIdx.x & 63) == 0) {
    atomicAdd(&ctl->posLoss, (double)posLoss);
    atomicAdd(&ctl->sumW, (double)sumW);
    atomicAdd(&ctl->posCount, posC);
    atomicAdd(&ctl->negCount, negC);
  }
  __syncthreads();
  for (int j = threadIdx.x; j < CBINS; j += TPB) {
    const unsigned c = lh[j];
    if (c) atomicAdd(&hist[j], c);   // zero-skip: ~1-2k populated bins
  }
}

// Find cutoff coarse bin: largest b with count(bins > b) < k <= count(bins >= b).
// Cooperative loads only — ws may be slow memory; avoid serial pointer-walks.
__global__ __launch_bounds__(256)
void scan_coarse(Ctl* __restrict__ ctl, const unsigned* __restrict__ hist)
{
  __shared__ unsigned chunk[256];
  __shared__ unsigned binv[32];
  __shared__ int s_cc;
  __shared__ unsigned s_A;
  __shared__ unsigned s_k;
  const int t = threadIdx.x;
  unsigned s = 0;
  #pragma unroll
  for (int j = 0; j < CBINS / 256; ++j) s += hist[t * (CBINS / 256) + j];
  chunk[t] = s;
  __syncthreads();
  if (t == 0) {
    const unsigned posC = ctl->posCount;
    const unsigned negC = ctl->negCount;
    const unsigned long long k3 = 3ull * (unsigned long long)posC;
    const unsigned k = (k3 < (unsigned long long)negC) ? (unsigned)k3 : negC;
    ctl->kSel = k;
    s_k = k;
    if (k == 0) { ctl->cutoffBin = 0xFFFFFFFFu; ctl->kRemain = 0; s_cc = -1; s_A = 0; }
    else {
      unsigned A = 0;
      int cc = 255;
      for (; cc >= 0; --cc) {
        if (A + chunk[cc] >= k) break;
        A += chunk[cc];
      }
      s_cc = cc; s_A = A;
    }
  }
  __syncthreads();
  const int cc = s_cc;
  if (cc < 0) return;
  if (t < 32) binv[t] = hist[cc * 32 + t];
  __syncthreads();
  if (t == 0) {
    unsigned A = s_A;
    const unsigned k = s_k;
    int j = 31;
    for (;; --j) {
      const unsigned c = binv[j];
      if (A + c >= k) break;
      A += c;
    }
    ctl->cutoffBin = (unsigned)(cc * 32 + j);
    ctl->kRemain = k - A;       // 1..hist[bin]
  }
}

// Pass 2: recompute se from inputs; exact sum above cutoff bin; fine histogram
// (counts + sums, next 12 mantissa bits) within cutoff bin.
__global__ __launch_bounds__(TPB)
void pass2(const float* __restrict__ pred, const float* __restrict__ vmk,
           const float* __restrict__ wgt, Ctl* __restrict__ ctl,
           unsigned* __restrict__ fcnt, float* __restrict__ fsum)
{
  __shared__ unsigned lc[FBINS];
  __shared__ float ls[FBINS];
  for (int j = threadIdx.x; j < FBINS; j += TPB) { lc[j] = 0; ls[j] = 0.f; }
  __syncthreads();

  const unsigned cut = ctl->cutoffBin;
  float above = 0.f;
  const int stride = gridDim.x * TPB;
  for (int g = blockIdx.x * TPB + threadIdx.x; g < N4; g += stride) {
    const int i = g << 2;
    const int b = i / HW;
    const int hw = i - b * HW;
    const size_t base = (size_t)b * (size_t)(2 * HW) + (size_t)hw;
    const float4 w4 = *(const float4*)(wgt + i);
    const float4 p0 = *(const float4*)(pred + base);
    const float4 p1 = *(const float4*)(pred + base + HW);
    const float4 t0 = *(const float4*)(vmk + base);
    const float4 t1 = *(const float4*)(vmk + base + HW);
    float se[4], wv[4];
    {
      float a, c;
      a = p0.x - t0.x; c = p1.x - t1.x; se[0] = a*a + c*c;
      a = p0.y - t0.y; c = p1.y - t1.y; se[1] = a*a + c*c;
      a = p0.z - t0.z; c = p1.z - t1.z; se[2] = a*a + c*c;
      a = p0.w - t0.w; c = p1.w - t1.w; se[3] = a*a + c*c;
    }
    wv[0] = w4.x; wv[1] = w4.y; wv[2] = w4.z; wv[3] = w4.w;
    #pragma unroll
    for (int c = 0; c < 4; ++c) {
      if (wv[c] == 0.f) {
        const float s = se[c];
        const unsigned bits = __float_as_uint(s);
        const unsigned bin = bits >> 19;
        if (bin > cut) above += s;
        else if (bin == cut) {
          const unsigned f = (bits >> 7) & (FBINS - 1);
          atomicAdd(&lc[f], 1u);
          atomicAdd(&ls[f], s);
        }
      }
    }
  }

  above = wredf(above);
  if ((threadIdx.x & 63) == 0) atomicAdd(&ctl->sumAbove, (double)above);
  __syncthreads();
  for (int j = threadIdx.x; j < FBINS; j += TPB) {
    const unsigned c = lc[j];
    if (c) { atomicAdd(&fcnt[j], c); atomicAdd(&fsum[j], ls[j]); }
  }
}

// Fine scan + final loss. Cooperative loads; thread0 only scans LDS.
__global__ __launch_bounds__(256)
void scan_finish(Ctl* __restrict__ ctl, const unsigned* __restrict__ fcnt,
                 const float* __restrict__ fsum, float* __restrict__ out)
{
  __shared__ unsigned chunk[256];
  __shared__ float chunkS[256];
  __shared__ unsigned binc[16];
  __shared__ float bins[16];
  __shared__ int s_cc;
  __shared__ unsigned s_A;
  __shared__ double s_S;
  const int t = threadIdx.x;
  unsigned s = 0; float ss = 0.f;
  #pragma unroll
  for (int j = 0; j < FBINS / 256; ++j) {
    s  += fcnt[t * (FBINS / 256) + j];
    ss += fsum[t * (FBINS / 256) + j];
  }
  chunk[t] = s; chunkS[t] = ss;
  __syncthreads();
  if (t == 0) {
    const unsigned kRem = ctl->kRemain;
    if (kRem == 0) { s_cc = -1; s_A = 0; s_S = 0.0; }
    else {
      unsigned A = 0; double S = 0.0;
      int cc = 255;
      for (; cc >= 0; --cc) {
        if (A + chunk[cc] >= kRem) break;
        A += chunk[cc]; S += (double)chunkS[cc];
      }
      s_cc = cc; s_A = A; s_S = S;
    }
  }
  __syncthreads();
  const int cc = s_cc;
  if (cc >= 0 && t < 16) {
    binc[t] = fcnt[cc * 16 + t];
    bins[t] = fsum[cc * 16 + t];
  }
  __syncthreads();
  if (t == 0) {
    double sel = 0.0;
    const unsigned kRem = ctl->kRemain;
    if (kRem > 0) {
      unsigned A = s_A; double S = s_S;
      int j = 15;
      for (;; --j) {
        const unsigned c = binc[j];
        if (A + c >= kRem) {
          const unsigned need = kRem - A;
          // crossing sub-bin: elements within 2^-16 relative width -> avg is (near-)exact
          sel = S + (double)bins[j] * ((double)need / (double)c);
          break;
        }
        A += c; S += (double)bins[j];
      }
    }
    const double num = ctl->posLoss + ctl->sumAbove + sel;
    const double den = 2.0 * ctl->sumW + 2.0 * (double)ctl->kSel;
    out[0] = (float)(num / den / 32.0);
  }
}

extern "C" void kernel_launch(void* const* d_in, const int* in_sizes, int n_in,
                              void* d_out, int out_size, void* d_ws, size_t ws_size,
                              hipStream_t stream)
{
  const float* pred = (const float*)d_in[0];
  const float* vmk  = (const float*)d_in[1];
  const float* wgt  = (const float*)d_in[2];
  char* ws = (char*)d_ws;
  Ctl* ctl       = (Ctl*)ws;
  unsigned* hist = (unsigned*)(ws + 64);
  unsigned* fcnt = (unsigned*)(ws + 64 + CBINS * 4);
  float* fsum    = (float*)(ws + 64 + CBINS * 4 + FBINS * 4);
  const size_t head = 64 + CBINS * 4 + FBINS * 4 + FBINS * 4;   // 65600 B

  hipMemsetAsync(d_ws, 0, head, stream);  // ws re-poisoned 0xAA before every call
  pass1<<<BLOCKS, TPB, 0, stream>>>(pred, vmk, wgt, ctl, hist);
  scan_coarse<<<1, 256, 0, stream>>>(ctl, hist);
  pass2<<<BLOCKS, TPB, 0, stream>>>(pred, vmk, wgt, ctl, fcnt, fsum);
  scan_finish<<<1, 256, 0, stream>>>(ctl, fcnt, fsum, (float*)d_out);
}

// Round 3
// 457.787 us; speedup vs baseline: 1.2473x; 1.2473x over previous
//
#include <hip/hip_runtime.h>

#define NROWS   13107200u        // 32*640*640
#define HW      409600u          // 640*640
#define N4      (NROWS/4u)       // 3,276,800 float4-groups
#define CBINS   8192             // top-13 bits of float(se): sign|8exp|4mant
#define TPB     256
#define BLOCKS  1280
#define THREADS (BLOCKS*TPB)     // 327,680 -> exactly 10 groups/thread
#define U       5                // groups per macro-iter (25 float4 loads in flight)

struct Ctl {
  double posLoss;     // sum over pos rows of se*w
  double sumW;        // sum over pos rows of w
  unsigned posCount;
  unsigned negCount;
  unsigned pad0, pad1;
};

__device__ inline float wredf(float v) {
  #pragma unroll
  for (int o = 32; o > 0; o >>= 1) v += __shfl_down(v, o, 64);
  return v;
}
__device__ inline unsigned wredu(unsigned v) {
  #pragma unroll
  for (int o = 32; o > 0; o >>= 1) v += (unsigned)__shfl_down((int)v, o, 64);
  return v;
}

// Single data pass: pos stats + per-coarse-bin {count, f32 sum} over negatives.
// Unroll x5: 25 independent dwordx4 loads issued before any consumption (MLP).
__global__ __launch_bounds__(TPB)
void mainpass(const float* __restrict__ pred, const float* __restrict__ vmk,
              const float* __restrict__ wgt, Ctl* __restrict__ ctl,
              unsigned* __restrict__ ghist, float* __restrict__ gsum)
{
  __shared__ unsigned lc[CBINS];
  __shared__ float    ls[CBINS];
  for (int j = threadIdx.x; j < CBINS; j += TPB) { lc[j] = 0; ls[j] = 0.f; }
  __syncthreads();

  float posLoss = 0.f, sumW = 0.f;
  unsigned posC = 0, negC = 0;
  const unsigned tid = blockIdx.x * TPB + threadIdx.x;

  #pragma unroll 1
  for (int m = 0; m < 2; ++m) {
    float4 w4[U], p0[U], p1[U], t0[U], t1[U];
    #pragma unroll
    for (int j = 0; j < U; ++j) {
      const unsigned g = tid + (unsigned)(m * U + j) * THREADS;
      const unsigned i = g << 2;
      const unsigned b = i / HW;            // 4-group never crosses batch (HW%4==0)
      const unsigned hw = i - b * HW;
      const size_t base = (size_t)b * (size_t)(2u * HW) + (size_t)hw;
      w4[j] = *(const float4*)(wgt + i);
      p0[j] = *(const float4*)(pred + base);
      p1[j] = *(const float4*)(pred + base + HW);
      t0[j] = *(const float4*)(vmk + base);
      t1[j] = *(const float4*)(vmk + base + HW);
    }
    #pragma unroll
    for (int j = 0; j < U; ++j) {
      float se[4], wv[4];
      {
        float a, c;
        a = p0[j].x - t0[j].x; c = p1[j].x - t1[j].x; se[0] = a*a + c*c;
        a = p0[j].y - t0[j].y; c = p1[j].y - t1[j].y; se[1] = a*a + c*c;
        a = p0[j].z - t0[j].z; c = p1[j].z - t1[j].z; se[2] = a*a + c*c;
        a = p0[j].w - t0[j].w; c = p1[j].w - t1[j].w; se[3] = a*a + c*c;
      }
      wv[0] = w4[j].x; wv[1] = w4[j].y; wv[2] = w4[j].z; wv[3] = w4[j].w;
      #pragma unroll
      for (int c = 0; c < 4; ++c) {
        const float w = wv[c];
        const float s = se[c];
        if (w > 0.f)       { posC++; sumW += w; posLoss += s * w; }
        else if (w == 0.f) {
          negC++;
          const unsigned bin = __float_as_uint(s) >> 19;
          atomicAdd(&lc[bin], 1u);
          atomicAdd(&ls[bin], s);
        }
        // w < 0: neither pos nor neg (mirrors reference semantics)
      }
    }
  }

  posLoss = wredf(posLoss); sumW = wredf(sumW);
  posC = wredu(posC); negC = wredu(negC);
  if ((threadIdx.x & 63) == 0) {
    atomicAdd(&ctl->posLoss, (double)posLoss);
    atomicAdd(&ctl->sumW, (double)sumW);
    atomicAdd(&ctl->posCount, posC);
    atomicAdd(&ctl->negCount, negC);
  }
  __syncthreads();
  for (int j = threadIdx.x; j < CBINS; j += TPB) {
    const unsigned c = lc[j];
    if (c) { atomicAdd(&ghist[j], c); atomicAdd(&gsum[j], ls[j]); }  // zero-skip
  }
}

// One block: suffix-scan histogram for cutoff, interpolate crossing bin, final loss.
__global__ __launch_bounds__(256)
void finish(Ctl* __restrict__ ctl, const unsigned* __restrict__ ghist,
            const float* __restrict__ gsum, float* __restrict__ out)
{
  __shared__ unsigned chunkC[256];
  __shared__ double   chunkS[256];
  __shared__ unsigned binC[32];
  __shared__ float    binS[32];
  __shared__ int s_cc;
  __shared__ unsigned s_A, s_k;
  __shared__ double s_S;
  const int t = threadIdx.x;
  {
    unsigned c = 0; double s = 0.0;
    #pragma unroll
    for (int j = 0; j < CBINS / 256; ++j) {
      c += ghist[t * (CBINS / 256) + j];
      s += (double)gsum[t * (CBINS / 256) + j];
    }
    chunkC[t] = c; chunkS[t] = s;
  }
  __syncthreads();
  if (t == 0) {
    const unsigned posC = ctl->posCount;
    const unsigned negC = ctl->negCount;
    const unsigned long long k3 = 3ull * (unsigned long long)posC;
    const unsigned k = (k3 < (unsigned long long)negC) ? (unsigned)k3 : negC;
    s_k = k;
    if (k == 0) { s_cc = -1; s_A = 0; s_S = 0.0; }
    else {
      unsigned A = 0; double S = 0.0;
      int cc = 255;
      for (; cc >= 0; --cc) {
        if (A + chunkC[cc] >= k) break;
        A += chunkC[cc]; S += chunkS[cc];
      }
      s_cc = cc; s_A = A; s_S = S;
    }
  }
  __syncthreads();
  const int cc = s_cc;
  if (cc >= 0 && t < 32) {
    binC[t] = ghist[cc * 32 + t];
    binS[t] = gsum[cc * 32 + t];
  }
  __syncthreads();
  if (t == 0) {
    const unsigned k = s_k;
    double sel = 0.0;
    if (k > 0) {
      unsigned A = s_A; double S = s_S;
      int j = 31;
      for (;; --j) {
        const unsigned c = binC[j];
        if (A + c >= k) {
          const unsigned need = k - A;
          const unsigned bi = (unsigned)(cc * 32 + j);
          // crossing bin [lo,hi): uniform-within-bin model for the top `need` of c
          const float lo = __uint_as_float(bi << 19);
          const float hi = __uint_as_float((bi + 1u) << 19);
          const double mu = (double)binS[j] / (double)c;
          const double q  = (double)need / (double)c;
          double em = mu + (1.0 - q) * 0.5 * ((double)hi - (double)lo);
          if (em > (double)hi) em = (double)hi;
          if (em < mu) em = mu;
          sel = S + (double)need * em;
          break;
        }
        A += c; S += (double)binS[j];
      }
    }
    const double num = ctl->posLoss + sel;
    double den = 2.0 * ctl->sumW + 2.0 * (double)k;
    if (den == 0.0) den = 1.0;
    out[0] = (float)(num / den / 32.0);
  }
}

extern "C" void kernel_launch(void* const* d_in, const int* in_sizes, int n_in,
                              void* d_out, int out_size, void* d_ws, size_t ws_size,
                              hipStream_t stream)
{
  const float* pred = (const float*)d_in[0];
  const float* vmk  = (const float*)d_in[1];
  const float* wgt  = (const float*)d_in[2];
  char* ws = (char*)d_ws;
  Ctl* ctl       = (Ctl*)ws;
  unsigned* ghist = (unsigned*)(ws + 64);
  float* gsum     = (float*)(ws + 64 + CBINS * 4);
  const size_t head = 64 + CBINS * 4 + CBINS * 4;   // 65,600 B

  hipMemsetAsync(d_ws, 0, head, stream);  // ws re-poisoned 0xAA before every call
  mainpass<<<BLOCKS, TPB, 0, stream>>>(pred, vmk, wgt, ctl, ghist, gsum);
  finish<<<1, 256, 0, stream>>>(ctl, ghist, gsum, (float*)d_out);
}

// Round 4
// 353.295 us; speedup vs baseline: 1.6162x; 1.2958x over previous
//
#include <hip/hip_runtime.h>

#define NROWS   13107200u        // 32*640*640
#define HW      409600u          // 640*640
#define N4      (NROWS/4u)       // 3,276,800 float4-groups
#define CBINS   4096             // bits(se)>>19: 8 exp + 4 mant (se >= 0, no sign)
#define DUMMY   4095u            // unused bin (max finite se ~242 -> bin ~2158); pos lanes go here
#define TPB     256
#define BLOCKS  1280
#define THREADS (BLOCKS*TPB)     // 327,680 -> exactly 10 groups/thread
#define ITERS   10

struct Ctl {
  double posLoss;     // sum of se*w over all elements (negs contribute 0; data has no w<0)
  double sumW;        // sum of w
};

__device__ inline float wredf(float v) {
  #pragma unroll
  for (int o = 32; o > 0; o >>= 1) v += __shfl_down(v, o, 64);
  return v;
}

// Single data pass. Branchless per-element body:
//   posLoss += se*w; sumW += w;                (w==0 for negatives)
//   hist[ w==0 ? bin(se) : DUMMY ] += 1        (one unconditional ds_add per element)
__global__ __launch_bounds__(TPB)
void mainpass(const float* __restrict__ pred, const float* __restrict__ vmk,
              const float* __restrict__ wgt, Ctl* __restrict__ ctl,
              unsigned* __restrict__ ghist)
{
  __shared__ unsigned lh[CBINS];
  #pragma unroll
  for (int j = 0; j < CBINS / TPB; ++j) lh[threadIdx.x + j * TPB] = 0;
  __syncthreads();

  float posLoss = 0.f, sumW = 0.f;
  const unsigned tid = blockIdx.x * TPB + threadIdx.x;

  #pragma unroll 1
  for (int m = 0; m < ITERS; ++m) {
    const unsigned g = tid + (unsigned)m * THREADS;
    const unsigned i = g << 2;
    const unsigned b = i / HW;            // 4-group never crosses batch (HW%4==0)
    const unsigned hw = i - b * HW;
    const size_t base = (size_t)b * (size_t)(2u * HW) + (size_t)hw;
    const float4 w4 = *(const float4*)(wgt + i);
    const float4 p0 = *(const float4*)(pred + base);
    const float4 p1 = *(const float4*)(pred + base + HW);
    const float4 t0 = *(const float4*)(vmk + base);
    const float4 t1 = *(const float4*)(vmk + base + HW);
    float se[4], wv[4];
    {
      float a, c;
      a = p0.x - t0.x; c = p1.x - t1.x; se[0] = a*a + c*c;
      a = p0.y - t0.y; c = p1.y - t1.y; se[1] = a*a + c*c;
      a = p0.z - t0.z; c = p1.z - t1.z; se[2] = a*a + c*c;
      a = p0.w - t0.w; c = p1.w - t1.w; se[3] = a*a + c*c;
    }
    wv[0] = w4.x; wv[1] = w4.y; wv[2] = w4.z; wv[3] = w4.w;
    #pragma unroll
    for (int c = 0; c < 4; ++c) {
      const float w = wv[c];
      const float s = se[c];
      posLoss = fmaf(s, w, posLoss);     // v_fmac
      sumW += w;                         // v_add
      const unsigned bin = __float_as_uint(s) >> 19;
      const unsigned idx = (w == 0.f) ? bin : DUMMY;   // cmp + cndmask
      atomicAdd(&lh[idx], 1u);           // unconditional ds_add_u32
    }
  }

  posLoss = wredf(posLoss); sumW = wredf(sumW);
  if ((threadIdx.x & 63) == 0) {
    atomicAdd(&ctl->posLoss, (double)posLoss);
    atomicAdd(&ctl->sumW, (double)sumW);
  }
  __syncthreads();
  #pragma unroll
  for (int j = 0; j < CBINS / TPB; ++j) {
    const int b = threadIdx.x + j * TPB;
    const unsigned c = lh[b];
    if (c) atomicAdd(&ghist[b], c);     // zero-skip: ~150 populated bins/block
  }
}

// One block: reconstruct per-bin sums as count*midpoint, suffix-scan for the
// OHEM cutoff, uniform-within-bin model for the crossing bin, final loss.
__global__ __launch_bounds__(256)
void finish(Ctl* __restrict__ ctl, const unsigned* __restrict__ ghist,
            float* __restrict__ out)
{
  __shared__ unsigned chunkC[256];
  __shared__ double   chunkS[256];
  __shared__ unsigned binC[16];
  __shared__ double   binS[16];
  __shared__ int s_cc;
  __shared__ unsigned s_A, s_k;
  __shared__ double s_S;
  const int t = threadIdx.x;
  const unsigned posC = ghist[DUMMY];

  {
    unsigned c = 0; double s = 0.0;
    #pragma unroll
    for (int j = 0; j < CBINS / 256; ++j) {
      const unsigned bi = (unsigned)(t * (CBINS / 256) + j);
      if (bi == DUMMY) continue;
      const unsigned cnt = ghist[bi];
      if (cnt) {        // guard: 0 * inf(bin of +inf) would be NaN
        const double lo = (double)__uint_as_float(bi << 19);
        const double hi = (double)__uint_as_float((bi + 1u) << 19);
        c += cnt;
        s += (double)cnt * 0.5 * (lo + hi);
      }
    }
    chunkC[t] = c; chunkS[t] = s;
  }
  __syncthreads();
  if (t == 0) {
    const unsigned negC = NROWS - posC;         // data has no w<0 / NaN weights
    const unsigned long long k3 = 3ull * (unsigned long long)posC;
    const unsigned k = (k3 < (unsigned long long)negC) ? (unsigned)k3 : negC;
    s_k = k;
    if (k == 0) { s_cc = -1; s_A = 0; s_S = 0.0; }
    else {
      unsigned A = 0; double S = 0.0;
      int cc = 255;
      for (; cc >= 0; --cc) {
        if (A + chunkC[cc] >= k) break;
        A += chunkC[cc]; S += chunkS[cc];
      }
      s_cc = cc; s_A = A; s_S = S;
    }
  }
  __syncthreads();
  const int cc = s_cc;
  if (cc >= 0 && t < 16) {
    const unsigned bi = (unsigned)(cc * 16 + t);
    unsigned cnt = (bi == DUMMY) ? 0u : ghist[bi];
    binC[t] = cnt;
    if (cnt) {
      const double lo = (double)__uint_as_float(bi << 19);
      const double hi = (double)__uint_as_float((bi + 1u) << 19);
      binS[t] = (double)cnt * 0.5 * (lo + hi);
    } else binS[t] = 0.0;
  }
  __syncthreads();
  if (t == 0) {
    const unsigned k = s_k;
    double sel = 0.0;
    if (k > 0) {
      unsigned A = s_A; double S = s_S;
      int j = 15;
      for (;; --j) {
        const unsigned c = binC[j];
        if (A + c >= k) {
          const unsigned need = k - A;
          const unsigned bi = (unsigned)(cc * 16 + j);
          const double lo = (double)__uint_as_float(bi << 19);
          const double hi = (double)__uint_as_float((bi + 1u) << 19);
          // uniform within [lo,hi): top `need` of c has mean hi - q*width/2
          const double q = (double)need / (double)c;
          sel = S + (double)need * (hi - 0.5 * q * (hi - lo));
          break;
        }
        A += c; S += binS[j];
      }
    }
    const double num = ctl->posLoss + sel;
    double den = 2.0 * ctl->sumW + 2.0 * (double)k;
    if (den == 0.0) den = 1.0;
    out[0] = (float)(num / den / 32.0);
  }
}

extern "C" void kernel_launch(void* const* d_in, const int* in_sizes, int n_in,
                              void* d_out, int out_size, void* d_ws, size_t ws_size,
                              hipStream_t stream)
{
  const float* pred = (const float*)d_in[0];
  const float* vmk  = (const float*)d_in[1];
  const float* wgt  = (const float*)d_in[2];
  char* ws = (char*)d_ws;
  Ctl* ctl        = (Ctl*)ws;
  unsigned* ghist = (unsigned*)(ws + 64);
  const size_t head = 64 + CBINS * 4;   // 16,448 B

  hipMemsetAsync(d_ws, 0, head, stream);  // ws re-poisoned 0xAA before every call
  mainpass<<<BLOCKS, TPB, 0, stream>>>(pred, vmk, wgt, ctl, ghist);
  finish<<<1, 256, 0, stream>>>(ctl, ghist, (float*)d_out);
}

// Round 5
// 297.497 us; speedup vs baseline: 1.9194x; 1.1876x over previous
//
#include <hip/hip_runtime.h>

#define NROWS   13107200u        // 32*640*640
#define HW      409600u          // 640*640
#define N4      (NROWS/4u)       // 3,276,800 float4-groups
#define CBINS   4096             // bits(se)>>19: 8 exp + 4 mant (se >= 0)
#define DUMMY   4095u            // unused bin (max se ~70 -> bin ~2150); pos lanes go here
#define NCOPY   4                // replicated LDS histograms (same-address decontention)
#define CSTRIDE 4097             // +1 skew: replicas of one bin land in different banks
#define TPB     256
#define BLOCKS  512              // exactly 2 blocks/CU resident at 64.1KB LDS
#define THREADS (BLOCKS*TPB)     // 131,072 -> exactly 25 groups/thread
#define ITERS   25

struct Ctl {
  double posLoss;     // sum of se*w over all elements (negs contribute 0)
  double sumW;        // sum of w
};

__device__ inline float wredf(float v) {
  #pragma unroll
  for (int o = 32; o > 0; o >>= 1) v += __shfl_down(v, o, 64);
  return v;
}

// Single data pass. Branchless per-element body:
//   posLoss += se*w; sumW += w;                     (w==0 for negatives)
//   lh[copy][ w==0 ? bin(se) : DUMMY ] += 1         (one unconditional ds_add)
// copy = lane&3 -> hot-bin same-address multiplicity /4; stride 4097 puts the
// 4 replicas in 4 different banks so they serialize in parallel banks.
__global__ __launch_bounds__(TPB)
void mainpass(const float* __restrict__ pred, const float* __restrict__ vmk,
              const float* __restrict__ wgt, Ctl* __restrict__ ctl,
              unsigned* __restrict__ ghist)
{
  __shared__ unsigned lh[NCOPY * CSTRIDE];   // 65,552 B
  for (int j = threadIdx.x; j < NCOPY * CSTRIDE; j += TPB) lh[j] = 0;
  __syncthreads();

  float posLoss = 0.f, sumW = 0.f;
  const unsigned tid = blockIdx.x * TPB + threadIdx.x;
  const unsigned copyOff = (threadIdx.x & (NCOPY - 1)) * CSTRIDE;

  #pragma unroll 1
  for (int m = 0; m < ITERS; ++m) {
    const unsigned g = tid + (unsigned)m * THREADS;
    const unsigned i = g << 2;
    const unsigned b = i / HW;            // 4-group never crosses batch (HW%4==0)
    const unsigned hw = i - b * HW;
    const size_t base = (size_t)b * (size_t)(2u * HW) + (size_t)hw;
    const float4 w4 = *(const float4*)(wgt + i);
    const float4 p0 = *(const float4*)(pred + base);
    const float4 p1 = *(const float4*)(pred + base + HW);
    const float4 t0 = *(const float4*)(vmk + base);
    const float4 t1 = *(const float4*)(vmk + base + HW);
    float se[4], wv[4];
    {
      float a, c;
      a = p0.x - t0.x; c = p1.x - t1.x; se[0] = a*a + c*c;
      a = p0.y - t0.y; c = p1.y - t1.y; se[1] = a*a + c*c;
      a = p0.z - t0.z; c = p1.z - t1.z; se[2] = a*a + c*c;
      a = p0.w - t0.w; c = p1.w - t1.w; se[3] = a*a + c*c;
    }
    wv[0] = w4.x; wv[1] = w4.y; wv[2] = w4.z; wv[3] = w4.w;
    #pragma unroll
    for (int c = 0; c < 4; ++c) {
      const float w = wv[c];
      const float s = se[c];
      posLoss = fmaf(s, w, posLoss);     // v_fmac
      sumW += w;                         // v_add
      const unsigned bin = __float_as_uint(s) >> 19;
      const unsigned idx = (w == 0.f) ? bin : DUMMY;   // cmp + cndmask
      atomicAdd(&lh[copyOff + idx], 1u); // unconditional ds_add_u32
    }
  }

  posLoss = wredf(posLoss); sumW = wredf(sumW);
  if ((threadIdx.x & 63) == 0) {
    atomicAdd(&ctl->posLoss, (double)posLoss);
    atomicAdd(&ctl->sumW, (double)sumW);
  }
  __syncthreads();
  for (int bn = threadIdx.x; bn < CBINS; bn += TPB) {
    unsigned c = 0;
    #pragma unroll
    for (int r = 0; r < NCOPY; ++r) c += lh[r * CSTRIDE + bn];
    if (c) atomicAdd(&ghist[bn], c);     // zero-skip: ~300 populated bins
  }
}

// One block: reconstruct per-bin sums as count*midpoint, suffix-scan for the
// OHEM cutoff, uniform-within-bin model for the crossing bin, final loss.
__global__ __launch_bounds__(256)
void finish(Ctl* __restrict__ ctl, const unsigned* __restrict__ ghist,
            float* __restrict__ out)
{
  __shared__ unsigned chunkC[256];
  __shared__ double   chunkS[256];
  __shared__ unsigned binC[16];
  __shared__ double   binS[16];
  __shared__ int s_cc;
  __shared__ unsigned s_A, s_k;
  __shared__ double s_S;
  const int t = threadIdx.x;
  const unsigned posC = ghist[DUMMY];

  {
    unsigned c = 0; double s = 0.0;
    #pragma unroll
    for (int j = 0; j < CBINS / 256; ++j) {
      const unsigned bi = (unsigned)(t * (CBINS / 256) + j);
      if (bi == DUMMY) continue;
      const unsigned cnt = ghist[bi];
      if (cnt) {        // guard: 0 * inf(bin of +inf) would be NaN
        const double lo = (double)__uint_as_float(bi << 19);
        const double hi = (double)__uint_as_float((bi + 1u) << 19);
        c += cnt;
        s += (double)cnt * 0.5 * (lo + hi);
      }
    }
    chunkC[t] = c; chunkS[t] = s;
  }
  __syncthreads();
  if (t == 0) {
    const unsigned negC = NROWS - posC;         // data has no w<0 / NaN weights
    const unsigned long long k3 = 3ull * (unsigned long long)posC;
    const unsigned k = (k3 < (unsigned long long)negC) ? (unsigned)k3 : negC;
    s_k = k;
    if (k == 0) { s_cc = -1; s_A = 0; s_S = 0.0; }
    else {
      unsigned A = 0; double S = 0.0;
      int cc = 255;
      for (; cc >= 0; --cc) {
        if (A + chunkC[cc] >= k) break;
        A += chunkC[cc]; S += chunkS[cc];
      }
      s_cc = cc; s_A = A; s_S = S;
    }
  }
  __syncthreads();
  const int cc = s_cc;
  if (cc >= 0 && t < 16) {
    const unsigned bi = (unsigned)(cc * 16 + t);
    unsigned cnt = (bi == DUMMY) ? 0u : ghist[bi];
    binC[t] = cnt;
    if (cnt) {
      const double lo = (double)__uint_as_float(bi << 19);
      const double hi = (double)__uint_as_float((bi + 1u) << 19);
      binS[t] = (double)cnt * 0.5 * (lo + hi);
    } else binS[t] = 0.0;
  }
  __syncthreads();
  if (t == 0) {
    const unsigned k = s_k;
    double sel = 0.0;
    if (k > 0) {
      unsigned A = s_A; double S = s_S;
      int j = 15;
      for (;; --j) {
        const unsigned c = binC[j];
        if (A + c >= k) {
          const unsigned need = k - A;
          const unsigned bi = (unsigned)(cc * 16 + j);
          const double lo = (double)__uint_as_float(bi << 19);
          const double hi = (double)__uint_as_float((bi + 1u) << 19);
          // uniform within [lo,hi): top `need` of c has mean hi - q*width/2
          const double q = (double)need / (double)c;
          sel = S + (double)need * (hi - 0.5 * q * (hi - lo));
          break;
        }
        A += c; S += binS[j];
      }
    }
    const double num = ctl->posLoss + sel;
    double den = 2.0 * ctl->sumW + 2.0 * (double)k;
    if (den == 0.0) den = 1.0;
    out[0] = (float)(num / den / 32.0);
  }
}

extern "C" void kernel_launch(void* const* d_in, const int* in_sizes, int n_in,
                              void* d_out, int out_size, void* d_ws, size_t ws_size,
                              hipStream_t stream)
{
  const float* pred = (const float*)d_in[0];
  const float* vmk  = (const float*)d_in[1];
  const float* wgt  = (const float*)d_in[2];
  char* ws = (char*)d_ws;
  Ctl* ctl        = (Ctl*)ws;
  unsigned* ghist = (unsigned*)(ws + 64);
  const size_t head = 64 + CBINS * 4;   // 16,448 B

  hipMemsetAsync(d_ws, 0, head, stream);  // ws re-poisoned 0xAA before every call
  mainpass<<<BLOCKS, TPB, 0, stream>>>(pred, vmk, wgt, ctl, ghist);
  finish<<<1, 256, 0, stream>>>(ctl, ghist, (float*)d_out);
}